// Round 5
// baseline (203.070 us; speedup 1.0000x reference)
//
#include <hip/hip_runtime.h>

// Sizes (fixed by the problem)
#define B_ 8192
#define T_ 256
#define I_ 28
#define H_ 10

// d_out layout: [B*T*H] output, then [2*B*H] h_final
#define OUT_MAIN (B_ * T_ * H_)   // 20971520
#define BH (B_ * H_)              // 81920

__device__ __forceinline__ float fast_tanh(float x) {
    // tanh(x) = 1 - 2/(exp(2x)+1); exp(2x) = exp2(x * 2*log2(e))
    float e = __builtin_amdgcn_exp2f(x * 2.885390081777927f);
    return __builtin_fmaf(-2.0f, __builtin_amdgcn_rcpf(e + 1.0f), 1.0f);
}

// ---------------- K1: xw0[b][t][u] = sum_i x[b][t][i] * Wih0[u][i] + (bih0[u]+bhh0[u])
// Memory-bound, ~roofline (~50 us, ~90% HBM). 2 rows (b,t) per thread, weights in LDS.
__global__ __launch_bounds__(256) void rnn_k1(
        const float* __restrict__ x, const float* __restrict__ Wih0,
        const float* __restrict__ bih0, const float* __restrict__ bhh0,
        float* __restrict__ xw0) {
    __shared__ float Wl[H_ * I_];
    __shared__ float bl[H_];
    int tid = threadIdx.x;
    for (int i = tid; i < H_ * I_; i += 256) Wl[i] = Wih0[i];  // 280 > 256: loop!
    if (tid < H_) bl[tid] = bih0[tid] + bhh0[tid];
    __syncthreads();

    long row0 = ((long)blockIdx.x * 256 + tid) * 2;
    const float* xr = x + row0 * I_;
    float xa[I_], xb[I_];
#pragma unroll
    for (int i = 0; i < 7; i++) {
        float4 va = ((const float4*)xr)[i];
        float4 vb = ((const float4*)(xr + I_))[i];
        xa[4*i+0] = va.x; xa[4*i+1] = va.y; xa[4*i+2] = va.z; xa[4*i+3] = va.w;
        xb[4*i+0] = vb.x; xb[4*i+1] = vb.y; xb[4*i+2] = vb.z; xb[4*i+3] = vb.w;
    }
    float oa[H_], ob[H_];
#pragma unroll
    for (int u = 0; u < H_; u++) {
        float s0 = bl[u], s1 = bl[u];
#pragma unroll
        for (int i = 0; i < I_; i++) {
            float w = Wl[u * I_ + i];
            s0 = __builtin_fmaf(xa[i], w, s0);
            s1 = __builtin_fmaf(xb[i], w, s1);
        }
        oa[u] = s0; ob[u] = s1;
    }
    float* o = xw0 + row0 * H_;
#pragma unroll
    for (int i = 0; i < 5; i++) {
        ((float2*)o)[i]        = make_float2(oa[2*i], oa[2*i+1]);
        ((float2*)(o + H_))[i] = make_float2(ob[2*i], ob[2*i+1]);
    }
}

// ---------------- K2: recurrent pass, DPP-ring (zero LDS/DS ops).
// 16 lanes per batch; lane j owns unit j (H padded to 16; pad lanes compute 0).
// r3 post-mortem: VGPR=36 -> weight loads remat'd inside loop. r4 (launch_bounds(256,2)
// + named scalars): VGPR=32, STILL remat'd -- launch_bounds only caps min waves/EU,
// the scheduler still targets max occupancy and sinks invariant loads.
// r5 fix: (a) amdgpu_waves_per_eu(2,2) sets the occupancy TARGET to what we launch;
// (b) asm-pin each weight VGPR -- an inline-asm def cannot be rematerialized.

template <int S>
__device__ __forceinline__ float rotf(float v) {
    return __int_as_float(__builtin_amdgcn_mov_dpp(
        __float_as_int(v), 0x120 + S, 0xF, 0xF, true));  // row_ror:S  (validated r3)
}

// named weight slot S of ring P from SRC (rotated row: P_S = W[j][(j-S)&15], 0 if pad)
#define WINIT(P, SRC, S) \
    float P##_##S = ((act) && (((j - (S)) & 15) < H_)) \
        ? SRC[j * H_ + ((j - (S)) & 15)] : 0.f;
#define WALL(P, SRC) \
    WINIT(P, SRC, 0)  WINIT(P, SRC, 1)  WINIT(P, SRC, 2)  WINIT(P, SRC, 3)  \
    WINIT(P, SRC, 4)  WINIT(P, SRC, 5)  WINIT(P, SRC, 6)  WINIT(P, SRC, 7)  \
    WINIT(P, SRC, 8)  WINIT(P, SRC, 9)  WINIT(P, SRC, 10) WINIT(P, SRC, 11) \
    WINIT(P, SRC, 12) WINIT(P, SRC, 13) WINIT(P, SRC, 14) WINIT(P, SRC, 15)

// anti-remat pin: value becomes the output of an opaque asm, must stay in a VGPR
#define PIN1(P, S) asm volatile("" : "+v"(P##_##S));
#define PINALL(P) \
    PIN1(P, 0)  PIN1(P, 1)  PIN1(P, 2)  PIN1(P, 3)  \
    PIN1(P, 4)  PIN1(P, 5)  PIN1(P, 6)  PIN1(P, 7)  \
    PIN1(P, 8)  PIN1(P, 9)  PIN1(P, 10) PIN1(P, 11) \
    PIN1(P, 12) PIN1(P, 13) PIN1(P, 14) PIN1(P, 15)

#define R1(acc, v, P, S) acc = __builtin_fmaf(rotf<S>(v), P##_##S, acc);
// chain slots 1..7 (acc seeded with slot 0)
#define CH_LO(acc, v, P) \
    R1(acc, v, P, 1) R1(acc, v, P, 2) R1(acc, v, P, 3) R1(acc, v, P, 4) \
    R1(acc, v, P, 5) R1(acc, v, P, 6) R1(acc, v, P, 7)
// chain slots 9..15 (acc seeded with slot 8)
#define CH_HI(acc, v, P) \
    R1(acc, v, P, 9)  R1(acc, v, P, 10) R1(acc, v, P, 11) R1(acc, v, P, 12) \
    R1(acc, v, P, 13) R1(acc, v, P, 14) R1(acc, v, P, 15)

__global__ __launch_bounds__(256)
__attribute__((amdgpu_waves_per_eu(2, 2)))
void rnn_k2(
        float* __restrict__ buf,            // d_out: xw0 in, output overwrites in place
        const float* __restrict__ h0in,     // [2][B][H]
        const float* __restrict__ Whh0, const float* __restrict__ Wih1,
        const float* __restrict__ Whh1,
        const float* __restrict__ bih1, const float* __restrict__ bhh1,
        float* __restrict__ hfin) {         // d_out + OUT_MAIN
    int id = blockIdx.x * 256 + threadIdx.x;
    int b = id >> 4;
    int j = id & 15;
    bool act = (j < H_);

    WALL(w0, Whh0)
    WALL(wi, Wih1)
    WALL(wh, Whh1)
    PINALL(w0)
    PINALL(wi)
    PINALL(wh)
    float bj  = act ? (bih1[j] + bhh1[j]) : 0.f;
    float h0v = act ? h0in[b * H_ + j] : 0.f;
    float h1v = act ? h0in[BH + b * H_ + j] : 0.f;
    asm volatile("" : "+v"(bj));

    float* base = buf + (long)b * (T_ * H_);
    float xb[4];
#pragma unroll
    for (int q = 0; q < 4; q++) xb[q] = act ? base[q * H_ + j] : 0.f;

    for (int t = 0; t < T_; t += 4) {
#pragma unroll
        for (int q = 0; q < 4; q++) {
            int tc = t + q;
            // prefetch 4 steps ahead (reads lead in-place writes by 4)
            float xnext = (tc + 4 < T_ && act) ? base[(tc + 4) * H_ + j] : 0.f;
            // layer 0: a = xw0 + Whh0 . h0   (2 chains of 8)
            float aA = __builtin_fmaf(h0v, w0_0, xb[q]);
            CH_LO(aA, h0v, w0)
            float aB = rotf<8>(h0v) * w0_8;
            CH_HI(aB, h0v, w0)
            float h0n = fast_tanh(aA + aB);
            // layer 1: c = b1 + Wih1 . h0n + Whh1 . h1   (4 chains of 8)
            float cA = __builtin_fmaf(h0n, wi_0, bj);
            CH_LO(cA, h0n, wi)
            float cB = rotf<8>(h0n) * wi_8;
            CH_HI(cB, h0n, wi)
            float cC = h1v * wh_0;
            CH_LO(cC, h1v, wh)
            float cD = rotf<8>(h1v) * wh_8;
            CH_HI(cD, h1v, wh)
            float h1n = fast_tanh((cA + cB) + (cC + cD));
            if (act) base[tc * H_ + j] = h1n;
            xb[q] = xnext;
            h0v = h0n; h1v = h1n;
        }
    }
    if (act) {
        hfin[b * H_ + j]      = h0v;
        hfin[BH + b * H_ + j] = h1v;
    }
}

extern "C" void kernel_launch(void* const* d_in, const int* in_sizes, int n_in,
                              void* d_out, int out_size, void* d_ws, size_t ws_size,
                              hipStream_t stream) {
    const float* x     = (const float*)d_in[0];
    const float* h0in  = (const float*)d_in[1];
    const float* Wih0  = (const float*)d_in[2];
    const float* Whh0  = (const float*)d_in[3];
    const float* bih0  = (const float*)d_in[4];
    const float* bhh0  = (const float*)d_in[5];
    const float* Wih1  = (const float*)d_in[6];
    const float* Whh1  = (const float*)d_in[7];
    const float* bih1  = (const float*)d_in[8];
    const float* bhh1  = (const float*)d_in[9];
    float* out = (float*)d_out;

    // K1: xw0 into d_out main region
    rnn_k1<<<dim3((B_ * T_) / 512), dim3(256), 0, stream>>>(x, Wih0, bih0, bhh0, out);
    // K2: 16 lanes/batch -> 131072 threads -> 512 blocks (2 waves/SIMD)
    rnn_k2<<<dim3(512), dim3(256), 0, stream>>>(out, h0in, Whh0, Wih1, Whh1,
                                                bih1, bhh1, out + OUT_MAIN);
}

// Round 6
// 172.368 us; speedup vs baseline: 1.1781x; 1.1781x over previous
//
#include <hip/hip_runtime.h>

// Sizes (fixed by the problem)
#define B_ 8192
#define T_ 256
#define I_ 28
#define H_ 10

// d_out layout: [B*T*H] output, then [2*B*H] h_final
#define OUT_MAIN (B_ * T_ * H_)   // 20971520
#define BH (B_ * H_)              // 81920

__device__ __forceinline__ float fast_tanh(float x) {
    // tanh(x) = 1 - 2/(exp(2x)+1); exp(2x) = exp2(x * 2*log2(e))
    float e = __builtin_amdgcn_exp2f(x * 2.885390081777927f);
    return __builtin_fmaf(-2.0f, __builtin_amdgcn_rcpf(e + 1.0f), 1.0f);
}

// ---------------- K1: xw0[b][t][u] = sum_i x[b][t][i] * Wih0[u][i] + (bih0[u]+bhh0[u])
// Memory-bound, ~roofline (~50 us, ~86% HBM). 2 rows (b,t) per thread, weights in LDS.
__global__ __launch_bounds__(256) void rnn_k1(
        const float* __restrict__ x, const float* __restrict__ Wih0,
        const float* __restrict__ bih0, const float* __restrict__ bhh0,
        float* __restrict__ xw0) {
    __shared__ float Wl[H_ * I_];
    __shared__ float bl[H_];
    int tid = threadIdx.x;
    for (int i = tid; i < H_ * I_; i += 256) Wl[i] = Wih0[i];  // 280 > 256: loop!
    if (tid < H_) bl[tid] = bih0[tid] + bhh0[tid];
    __syncthreads();

    long row0 = ((long)blockIdx.x * 256 + tid) * 2;
    const float* xr = x + row0 * I_;
    float xa[I_], xb[I_];
#pragma unroll
    for (int i = 0; i < 7; i++) {
        float4 va = ((const float4*)xr)[i];
        float4 vb = ((const float4*)(xr + I_))[i];
        xa[4*i+0] = va.x; xa[4*i+1] = va.y; xa[4*i+2] = va.z; xa[4*i+3] = va.w;
        xb[4*i+0] = vb.x; xb[4*i+1] = vb.y; xb[4*i+2] = vb.z; xb[4*i+3] = vb.w;
    }
    float oa[H_], ob[H_];
#pragma unroll
    for (int u = 0; u < H_; u++) {
        float s0 = bl[u], s1 = bl[u];
#pragma unroll
        for (int i = 0; i < I_; i++) {
            float w = Wl[u * I_ + i];
            s0 = __builtin_fmaf(xa[i], w, s0);
            s1 = __builtin_fmaf(xb[i], w, s1);
        }
        oa[u] = s0; ob[u] = s1;
    }
    float* o = xw0 + row0 * H_;
#pragma unroll
    for (int i = 0; i < 5; i++) {
        ((float2*)o)[i]        = make_float2(oa[2*i], oa[2*i+1]);
        ((float2*)(o + H_))[i] = make_float2(ob[2*i], ob[2*i+1]);
    }
}

// ---------------- K2: recurrent pass, DPP-ring via hand-written v_fmac_f32_dpp.
// 16 lanes per batch; lane j owns unit j (H padded to 16; pad lanes compute 0).
// r5 post-mortem: weights resident (VGPR 88) but dur unchanged -> per-step issue
// ~225 inst-equiv/wave-step, ~2x source count: DPP movs not fused into FMAs.
// r6 fix: the ring is inline-asm v_fmac_f32_dpp (acc += (h row_ror:S) * w), one
// instruction per slot. Hazard: only h0n is consumed via DPP <2 insts after its
// VALU def -> s_nop 1 dependency-tied through h0n. All other DPP sources are
// defined a full ring earlier; accumulator RAW is interlocked (non-DPP read).

// named weight slot S of ring P from SRC (rotated row: P_S = W[j][(j-S)&15], 0 if pad)
#define WINIT(P, SRC, S) \
    float P##_##S = ((act) && (((j - (S)) & 15) < H_)) \
        ? SRC[j * H_ + ((j - (S)) & 15)] : 0.f;
#define WALL(P, SRC) \
    WINIT(P, SRC, 0)  WINIT(P, SRC, 1)  WINIT(P, SRC, 2)  WINIT(P, SRC, 3)  \
    WINIT(P, SRC, 4)  WINIT(P, SRC, 5)  WINIT(P, SRC, 6)  WINIT(P, SRC, 7)  \
    WINIT(P, SRC, 8)  WINIT(P, SRC, 9)  WINIT(P, SRC, 10) WINIT(P, SRC, 11) \
    WINIT(P, SRC, 12) WINIT(P, SRC, 13) WINIT(P, SRC, 14) WINIT(P, SRC, 15)

// anti-remat pin: value becomes the output of an opaque asm, must stay in a VGPR
#define PIN1(P, S) asm volatile("" : "+v"(P##_##S));
#define PINALL(P) \
    PIN1(P, 0)  PIN1(P, 1)  PIN1(P, 2)  PIN1(P, 3)  \
    PIN1(P, 4)  PIN1(P, 5)  PIN1(P, 6)  PIN1(P, 7)  \
    PIN1(P, 8)  PIN1(P, 9)  PIN1(P, 10) PIN1(P, 11) \
    PIN1(P, 12) PIN1(P, 13) PIN1(P, 14) PIN1(P, 15)

// fused DPP-FMA: acc += (h rotated by S over the 16-lane row) * w
// row_ror:S == dpp_ctrl 0x120+S, same semantics as the r3-validated intrinsic path.
#define FMACD(acc, h, w, S) \
    asm("v_fmac_f32_dpp %0, %1, %2 row_ror:" #S " row_mask:0xf bank_mask:0xf" \
        : "+v"(acc) : "v"(h), "v"(w));

#define CHLO_A(acc, h, P) \
    FMACD(acc, h, P##_1, 1) FMACD(acc, h, P##_2, 2) FMACD(acc, h, P##_3, 3) \
    FMACD(acc, h, P##_4, 4) FMACD(acc, h, P##_5, 5) FMACD(acc, h, P##_6, 6) \
    FMACD(acc, h, P##_7, 7)
#define CHHI_A(acc, h, P) \
    FMACD(acc, h, P##_8, 8)   FMACD(acc, h, P##_9, 9)   FMACD(acc, h, P##_10, 10) \
    FMACD(acc, h, P##_11, 11) FMACD(acc, h, P##_12, 12) FMACD(acc, h, P##_13, 13) \
    FMACD(acc, h, P##_14, 14) FMACD(acc, h, P##_15, 15)

__global__ __launch_bounds__(256)
__attribute__((amdgpu_waves_per_eu(2, 2)))
void rnn_k2(
        float* __restrict__ buf,            // d_out: xw0 in, output overwrites in place
        const float* __restrict__ h0in,     // [2][B][H]
        const float* __restrict__ Whh0, const float* __restrict__ Wih1,
        const float* __restrict__ Whh1,
        const float* __restrict__ bih1, const float* __restrict__ bhh1,
        float* __restrict__ hfin) {         // d_out + OUT_MAIN
    int id = blockIdx.x * 256 + threadIdx.x;
    int b = id >> 4;
    int j = id & 15;
    bool act = (j < H_);
    int jl = act ? j : (H_ - 1);            // lane clamp: pad lanes duplicate lane 9

    WALL(w0, Whh0)
    WALL(wi, Wih1)
    WALL(wh, Whh1)
    PINALL(w0)
    PINALL(wi)
    PINALL(wh)
    float bj  = act ? (bih1[j] + bhh1[j]) : 0.f;
    float h0v = act ? h0in[b * H_ + j] : 0.f;
    float h1v = act ? h0in[BH + b * H_ + j] : 0.f;
    asm volatile("" : "+v"(bj));

    float* base = buf + (long)b * (T_ * H_);
    const float* pf = base + jl;            // prefetch pointer (clamped lane)
    float xb[4];
#pragma unroll
    for (int q = 0; q < 4; q++) xb[q] = pf[q * H_];

    for (int t = 0; t < T_; t += 4) {
#pragma unroll
        for (int q = 0; q < 4; q++) {
            int tc = t + q;
            // prefetch 4 steps ahead (reads lead in-place writes by 4; clamp is safe:
            // slot T-1 is only overwritten at step T-1, after every real read of it)
            int tpre = tc + 4 < T_ ? tc + 4 : T_ - 1;   // uniform
            float xnext = pf[tpre * H_];
            // layer 0: a = xw0 + Whh0 . h0   (2 chains of 8)
            float aA = __builtin_fmaf(h0v, w0_0, xb[q]);
            float aB = 0.f;
            CHLO_A(aA, h0v, w0)
            CHHI_A(aB, h0v, w0)
            float h0n = fast_tanh(aA + aB);
            // DPP hazard guard: h0n is read via DPP immediately below
            asm volatile("s_nop 1" : "+v"(h0n));
            // layer 1: c = b1 + Wih1 . h0n + Whh1 . h1   (4 chains of 8)
            float cA = __builtin_fmaf(h0n, wi_0, bj);
            float cB = 0.f;
            float cC = h1v * wh_0;
            float cD = 0.f;
            CHLO_A(cA, h0n, wi)
            CHHI_A(cB, h0n, wi)
            CHLO_A(cC, h1v, wh)
            CHHI_A(cD, h1v, wh)
            float h1n = fast_tanh((cA + cB) + (cC + cD));
            if (act) base[tc * H_ + j] = h1n;
            xb[q] = xnext;
            h0v = h0n; h1v = h1n;
        }
    }
    if (act) {
        hfin[b * H_ + j]      = h0v;
        hfin[BH + b * H_ + j] = h1v;
    }
}

extern "C" void kernel_launch(void* const* d_in, const int* in_sizes, int n_in,
                              void* d_out, int out_size, void* d_ws, size_t ws_size,
                              hipStream_t stream) {
    const float* x     = (const float*)d_in[0];
    const float* h0in  = (const float*)d_in[1];
    const float* Wih0  = (const float*)d_in[2];
    const float* Whh0  = (const float*)d_in[3];
    const float* bih0  = (const float*)d_in[4];
    const float* bhh0  = (const float*)d_in[5];
    const float* Wih1  = (const float*)d_in[6];
    const float* Whh1  = (const float*)d_in[7];
    const float* bih1  = (const float*)d_in[8];
    const float* bhh1  = (const float*)d_in[9];
    float* out = (float*)d_out;

    // K1: xw0 into d_out main region
    rnn_k1<<<dim3((B_ * T_) / 512), dim3(256), 0, stream>>>(x, Wih0, bih0, bhh0, out);
    // K2: 16 lanes/batch -> 131072 threads -> 512 blocks (2 waves/SIMD)
    rnn_k2<<<dim3(512), dim3(256), 0, stream>>>(out, h0in, Whh0, Wih1, Whh1,
                                                bih1, bhh1, out + OUT_MAIN);
}